// Round 1
// baseline (2840.752 us; speedup 1.0000x reference)
//
#include <hip/hip_runtime.h>

#define N_ 16384
#define E_ 262144
#define C_ 256
#define R_ 9
#define B_ 4

typedef unsigned short u16;
typedef unsigned int u32;

typedef __bf16 bf16x8 __attribute__((ext_vector_type(8)));
typedef float f32x4 __attribute__((ext_vector_type(4)));

__device__ __forceinline__ u16 f2bf(float x) {
  u32 u = __float_as_uint(x);
  u32 r = (u + 0x7fffu + ((u >> 16) & 1u)) >> 16;  // RNE
  return (u16)r;
}
__device__ __forceinline__ float bf2f(u16 h) {
  return __uint_as_float(((u32)h) << 16);
}
// monotone float<->uint for atomicMax-based segment max
__device__ __forceinline__ u32 flipf(float x) {
  u32 u = __float_as_uint(x);
  return (u & 0x80000000u) ? ~u : (u | 0x80000000u);
}
__device__ __forceinline__ float unflipf(u32 u) {
  return (u & 0x80000000u) ? __uint_as_float(u & 0x7fffffffu) : __uint_as_float(~u);
}

// ---------------------------------------------------------------------------
// prep: W_t[r][o][c] (or stacked W_t[o][r*256+c]) = sum_b att[r,b]*basis[b,c,o]
// ---------------------------------------------------------------------------
__global__ void prep_w_kernel(const float* __restrict__ basis,
                              const float* __restrict__ att,
                              u16* __restrict__ out, int stacked) {
  int c = blockIdx.x;    // 0..255 (input channel = K index)
  int r = blockIdx.y;    // 0..8
  int o = threadIdx.x;   // 0..255 (output channel = N index)
  float s = 0.f;
#pragma unroll
  for (int b = 0; b < B_; ++b)
    s += att[r * B_ + b] * basis[((long)b * C_ + c) * C_ + o];
  u16 h = f2bf(s);
  if (stacked) out[(long)o * (R_ * C_) + r * C_ + c] = h;   // Bt[n=o][k=r*256+c], K=2304
  else         out[((long)r * C_ + o) * C_ + c] = h;        // per-batch Bt[n=o][k=c], K=256
}

// v[r][c] = sum_o W[r][c][o] * aw[r][o]
__global__ void prep_v_kernel(const float* __restrict__ basis,
                              const float* __restrict__ att,
                              const float* __restrict__ aw,
                              float* __restrict__ v) {
  int c = blockIdx.x, r = blockIdx.y, o = threadIdx.x;
  float w = 0.f;
#pragma unroll
  for (int b = 0; b < B_; ++b)
    w += att[r * B_ + b] * basis[((long)b * C_ + c) * C_ + o];
  float p = w * aw[r * C_ + o];
  __shared__ float red[256];
  red[o] = p;
  __syncthreads();
  for (int s = 128; s > 0; s >>= 1) {
    if (o < s) red[o] += red[o + s];
    __syncthreads();
  }
  if (o == 0) v[r * C_ + c] = red[0];
}

__global__ void cvt_bf16_kernel(const float* __restrict__ in, u16* __restrict__ out) {
  long i = ((long)blockIdx.x * 256 + threadIdx.x) * 4;
  float4 f = *(const float4*)(in + i);
  ushort4 h;
  h.x = f2bf(f.x); h.y = f2bf(f.y); h.z = f2bf(f.z); h.w = f2bf(f.w);
  *(ushort4*)(out + i) = h;
}

// ---------------------------------------------------------------------------
// GEMM: Out[m][n] = sum_k A[m][k] * Bt[n][k]   (Bt is N-major, bf16)
// Tile 128x128x32, 4 waves (2x2), each wave 4x4 mfma_f32_16x16x32_bf16
// ---------------------------------------------------------------------------
#define BM 128
#define BN 128
#define BK 32
#define LSTR 40  // padded LDS row stride (u16 elems)

template <int ABF16, int OBF16>
__global__ __launch_bounds__(256) void gemm_kernel(
    const void* __restrict__ Av, long aBatch, int lda,
    const u16* __restrict__ Bt, long bBatch, int K,
    void* __restrict__ Out, long cBatch, int ldc) {
  __shared__ __attribute__((aligned(16))) u16 As[BM * LSTR];
  __shared__ __attribute__((aligned(16))) u16 Bs[BN * LSTR];

  const int t = threadIdx.x;
  const int m0 = blockIdx.x * BM;
  const int n0 = blockIdx.y * BN;
  const long zb = blockIdx.z;

  const int tr = t >> 1;          // staging row 0..127
  const int th = (t & 1) * 16;    // staging k-offset 0/16

  const int w = t >> 6, lane = t & 63;
  const int wm = (w >> 1) * 64, wn = (w & 1) * 64;
  const int lr = lane & 15;
  const int lk = (lane >> 4) * 8;

  f32x4 acc[4][4];
#pragma unroll
  for (int i = 0; i < 4; ++i)
#pragma unroll
    for (int j = 0; j < 4; ++j) acc[i][j] = (f32x4){0.f, 0.f, 0.f, 0.f};

  const float* aRowF = (const float*)Av + zb * aBatch + (long)(m0 + tr) * lda + th;
  const u16* aRowH = (const u16*)Av + zb * aBatch + (long)(m0 + tr) * lda + th;
  const u16* bRow = Bt + zb * bBatch + (long)(n0 + tr) * K + th;

  u16* aDst = &As[tr * LSTR + th];
  u16* bDst = &Bs[tr * LSTR + th];

  for (int k0 = 0; k0 < K; k0 += BK) {
    if (ABF16) {
      int4 v0 = *(const int4*)(aRowH);
      int4 v1 = *(const int4*)(aRowH + 8);
      *(int4*)(aDst) = v0;
      *(int4*)(aDst + 8) = v1;
      aRowH += BK;
    } else {
      float4 f0 = *(const float4*)(aRowF + 0);
      float4 f1 = *(const float4*)(aRowF + 4);
      float4 f2 = *(const float4*)(aRowF + 8);
      float4 f3 = *(const float4*)(aRowF + 12);
      int4 p, q;
      p.x = (int)((u32)f2bf(f0.x) | ((u32)f2bf(f0.y) << 16));
      p.y = (int)((u32)f2bf(f0.z) | ((u32)f2bf(f0.w) << 16));
      p.z = (int)((u32)f2bf(f1.x) | ((u32)f2bf(f1.y) << 16));
      p.w = (int)((u32)f2bf(f1.z) | ((u32)f2bf(f1.w) << 16));
      q.x = (int)((u32)f2bf(f2.x) | ((u32)f2bf(f2.y) << 16));
      q.y = (int)((u32)f2bf(f2.z) | ((u32)f2bf(f2.w) << 16));
      q.z = (int)((u32)f2bf(f3.x) | ((u32)f2bf(f3.y) << 16));
      q.w = (int)((u32)f2bf(f3.z) | ((u32)f2bf(f3.w) << 16));
      *(int4*)(aDst) = p;
      *(int4*)(aDst + 8) = q;
      aRowF += BK;
    }
    {
      int4 b0 = *(const int4*)(bRow);
      int4 b1 = *(const int4*)(bRow + 8);
      *(int4*)(bDst) = b0;
      *(int4*)(bDst + 8) = b1;
      bRow += BK;
    }
    __syncthreads();

    bf16x8 af[4], bg[4];
#pragma unroll
    for (int mi = 0; mi < 4; ++mi)
      af[mi] = *(const bf16x8*)&As[(wm + mi * 16 + lr) * LSTR + lk];
#pragma unroll
    for (int ni = 0; ni < 4; ++ni)
      bg[ni] = *(const bf16x8*)&Bs[(wn + ni * 16 + lr) * LSTR + lk];
#pragma unroll
    for (int mi = 0; mi < 4; ++mi)
#pragma unroll
      for (int ni = 0; ni < 4; ++ni)
        acc[mi][ni] = __builtin_amdgcn_mfma_f32_16x16x32_bf16(af[mi], bg[ni], acc[mi][ni], 0, 0, 0);

    __syncthreads();
  }

  long base = zb * cBatch;
#pragma unroll
  for (int mi = 0; mi < 4; ++mi) {
    int rowb = m0 + wm + mi * 16 + ((lane >> 4) * 4);
#pragma unroll
    for (int ni = 0; ni < 4; ++ni) {
      int col = n0 + wn + ni * 16 + lr;
      f32x4 c = acc[mi][ni];
#pragma unroll
      for (int i = 0; i < 4; ++i) {
        long idx = base + (long)(rowb + i) * ldc + col;
        if (OBF16) ((u16*)Out)[idx] = f2bf(c[i]);
        else ((float*)Out)[idx] = c[i];
      }
    }
  }
}

// ---------------------------------------------------------------------------
// rel_emb[e] = ef[e] + 0.5*(Ysub[et[e]][src[e]] + Yobj[eti[e]][dst[e]])
// 1 wave per edge, lane covers 4 channels
// ---------------------------------------------------------------------------
__global__ __launch_bounds__(256) void relemb_kernel(
    const float* __restrict__ ef, const u16* __restrict__ Ysub,
    const u16* __restrict__ Yobj, const int* __restrict__ src,
    const int* __restrict__ dst, const int* __restrict__ et,
    const int* __restrict__ eti, float* __restrict__ rel) {
  int e = blockIdx.x * 4 + (threadIdx.x >> 6);
  int lane = threadIdx.x & 63;
  int c = lane * 4;
  long rsub = ((long)et[e] * N_ + src[e]) * C_ + c;
  long robj = ((long)eti[e] * N_ + dst[e]) * C_ + c;
  ushort4 ys = *(const ushort4*)(Ysub + rsub);
  ushort4 yo = *(const ushort4*)(Yobj + robj);
  long ei = (long)e * C_ + c;
  float4 f = *(const float4*)(ef + ei);
  float4 o;
  o.x = f.x + 0.5f * (bf2f(ys.x) + bf2f(yo.x));
  o.y = f.y + 0.5f * (bf2f(ys.y) + bf2f(yo.y));
  o.z = f.z + 0.5f * (bf2f(ys.z) + bf2f(yo.z));
  o.w = f.w + 0.5f * (bf2f(ys.w) + bf2f(yo.w));
  *(float4*)(rel + ei) = o;
}

// ---------------------------------------------------------------------------
// score[e] = leaky_relu(rel[e].v[rt] + ab[rt]); segment max + count
// ---------------------------------------------------------------------------
__global__ __launch_bounds__(256) void score_kernel(
    const float* __restrict__ rel, const float* __restrict__ v,
    const float* __restrict__ ab, const int* __restrict__ etype,
    const int* __restrict__ seg, float* __restrict__ score,
    u32* __restrict__ smax, int* __restrict__ cnt) {
  int e = blockIdx.x * 4 + (threadIdx.x >> 6);
  int lane = threadIdx.x & 63;
  int rt = etype[e];
  float4 x = *(const float4*)(rel + (long)e * C_ + lane * 4);
  float4 w = *(const float4*)(v + rt * C_ + lane * 4);
  float p = x.x * w.x + x.y * w.y + x.z * w.z + x.w * w.w;
#pragma unroll
  for (int off = 32; off > 0; off >>= 1) p += __shfl_xor(p, off);
  if (lane == 0) {
    float s = p + ab[rt];
    s = s > 0.f ? s : 0.01f * s;
    int key = seg[e] * R_ + rt;
    score[e] = s;
    atomicMax(&smax[key], flipf(s));
    atomicAdd(&cnt[key], 1);
  }
}

__global__ __launch_bounds__(256) void expsum_kernel(
    const u32* __restrict__ smax, float* __restrict__ score,
    float* __restrict__ den, const int* __restrict__ etype,
    const int* __restrict__ seg) {
  int e = blockIdx.x * 256 + threadIdx.x;
  int key = seg[e] * R_ + etype[e];
  float mx = unflipf(smax[key]);
  float ex = expf(score[e] - mx);
  score[e] = ex;
  atomicAdd(&den[key], ex);
}

// z[key][c] += alpha * rel[e][c]
__global__ __launch_bounds__(256) void zbuild_kernel(
    const float* __restrict__ rel, const float* __restrict__ ex,
    const float* __restrict__ den, const int* __restrict__ etype,
    const int* __restrict__ seg, float* __restrict__ z) {
  int e = blockIdx.x * 4 + (threadIdx.x >> 6);
  int lane = threadIdx.x & 63;
  int key = seg[e] * R_ + etype[e];
  float alpha = ex[e] / den[key];
  int c = lane * 4;
  float4 x = *(const float4*)(rel + (long)e * C_ + c);
  float* zp = z + (long)key * C_ + c;
  atomicAdd(zp + 0, alpha * x.x);
  atomicAdd(zp + 1, alpha * x.y);
  atomicAdd(zp + 2, alpha * x.z);
  atomicAdd(zp + 3, alpha * x.w);
}

__global__ __launch_bounds__(256) void final_kernel(
    const float* __restrict__ nf, const float* __restrict__ aggS,
    const float* __restrict__ aggO, const int* __restrict__ cntS,
    const int* __restrict__ cntO, float* __restrict__ node) {
  int n = blockIdx.x, c = threadIdx.x;
  int ds = 0, dobj = 0;
#pragma unroll
  for (int r = 0; r < R_; ++r) {
    ds += (cntS[n * R_ + r] > 0);
    dobj += (cntO[n * R_ + r] > 0);
  }
  float fs = ds ? (float)ds : 1.f;
  float fo = dobj ? (float)dobj : 1.f;
  long i = (long)n * C_ + c;
  node[i] = nf[i] + 0.5f * (aggS[i] / fs + aggO[i] / fo);
}

// ---------------------------------------------------------------------------
extern "C" void kernel_launch(void* const* d_in, const int* in_sizes, int n_in,
                              void* d_out, int out_size, void* d_ws, size_t ws_size,
                              hipStream_t stream) {
  const int* edge_index = (const int*)d_in[0];
  const float* nf = (const float*)d_in[1];
  const float* ef = (const float*)d_in[2];
  const int* et = (const int*)d_in[3];
  const int* eti = (const int*)d_in[4];
  const float* s2r_basis = (const float*)d_in[6];
  const float* s2r_att = (const float*)d_in[7];
  const float* o2r_basis = (const float*)d_in[8];
  const float* o2r_att = (const float*)d_in[9];
  const float* r2s_basis = (const float*)d_in[10];
  const float* r2s_att = (const float*)d_in[11];
  const float* r2s_aw = (const float*)d_in[12];
  const float* r2s_ab = (const float*)d_in[13];
  const float* r2o_basis = (const float*)d_in[14];
  const float* r2o_att = (const float*)d_in[15];
  const float* r2o_aw = (const float*)d_in[16];
  const float* r2o_ab = (const float*)d_in[17];

  const int* src = edge_index;
  const int* dst = edge_index + E_;

  char* ws = (char*)d_ws;
  u16* WtSub = (u16*)(ws + 0);
  u16* WtObj = (u16*)(ws + 1179648);
  u16* WtR2S = (u16*)(ws + 2359296);
  u16* WtR2O = (u16*)(ws + 3538944);
  float* vS = (float*)(ws + 4718592);
  float* vO = (float*)(ws + 4727808);
  u16* nfb = (u16*)(ws + 4737024);
  float* score = (float*)(ws + 13125632);
  u32* smaxS = (u32*)(ws + 14174208);
  float* denS = (float*)(ws + 14764032);
  int* cntS = (int*)(ws + 15353856);
  u32* smaxO = (u32*)(ws + 15943680);
  float* denO = (float*)(ws + 16533504);
  int* cntO = (int*)(ws + 17123328);
  float* aggS = (float*)(ws + 17713152);
  float* aggO = (float*)(ws + 34490368);
  char* big = ws + 51267584;  // 150,994,944 B: Ysub(bf16)+Yobj(bf16), later z(f32)
  u16* Ysub = (u16*)big;
  u16* Yobj = (u16*)(big + 75497472);
  float* zbuf = (float*)big;

  float* node_out = (float*)d_out;
  float* rel_out = (float*)d_out + (long)N_ * C_;

  // ---- prep (weights, score vectors, nf->bf16) ----
  prep_w_kernel<<<dim3(C_, R_), 256, 0, stream>>>(s2r_basis, s2r_att, WtSub, 0);
  prep_w_kernel<<<dim3(C_, R_), 256, 0, stream>>>(o2r_basis, o2r_att, WtObj, 0);
  prep_w_kernel<<<dim3(C_, R_), 256, 0, stream>>>(r2s_basis, r2s_att, WtR2S, 1);
  prep_w_kernel<<<dim3(C_, R_), 256, 0, stream>>>(r2o_basis, r2o_att, WtR2O, 1);
  prep_v_kernel<<<dim3(C_, R_), 256, 0, stream>>>(r2s_basis, r2s_att, r2s_aw, vS);
  prep_v_kernel<<<dim3(C_, R_), 256, 0, stream>>>(r2o_basis, r2o_att, r2o_aw, vO);
  cvt_bf16_kernel<<<(N_ * C_) / 1024, 256, 0, stream>>>(nf, nfb);
  hipMemsetAsync(smaxS, 0, 6L * 589824, stream);  // smaxS..cntO contiguous

  // ---- Y[r] = nf @ W_r (batched over r), bf16 out ----
  gemm_kernel<1, 1><<<dim3(N_ / BM, C_ / BN, R_), 256, 0, stream>>>(
      nfb, 0L, C_, WtSub, (long)C_ * C_, C_, Ysub, (long)N_ * C_, C_);
  gemm_kernel<1, 1><<<dim3(N_ / BM, C_ / BN, R_), 256, 0, stream>>>(
      nfb, 0L, C_, WtObj, (long)C_ * C_, C_, Yobj, (long)N_ * C_, C_);

  // ---- rel_emb ----
  relemb_kernel<<<E_ / 4, 256, 0, stream>>>(ef, Ysub, Yobj, src, dst, et, eti, rel_out);

  // ---- branch rel2sub: etypes = eti, seg = src ----
  hipMemsetAsync(zbuf, 0, 150994944, stream);
  score_kernel<<<E_ / 4, 256, 0, stream>>>(rel_out, vS, r2s_ab, eti, src, score, smaxS, cntS);
  expsum_kernel<<<E_ / 256, 256, 0, stream>>>(smaxS, score, denS, eti, src);
  zbuild_kernel<<<E_ / 4, 256, 0, stream>>>(rel_out, score, denS, eti, src, zbuf);
  gemm_kernel<0, 0><<<dim3(N_ / BM, C_ / BN, 1), 256, 0, stream>>>(
      zbuf, 0L, R_ * C_, WtR2S, 0L, R_ * C_, aggS, 0L, C_);

  // ---- branch rel2obj: etypes = et, seg = dst ----
  hipMemsetAsync(zbuf, 0, 150994944, stream);
  score_kernel<<<E_ / 4, 256, 0, stream>>>(rel_out, vO, r2o_ab, et, dst, score, smaxO, cntO);
  expsum_kernel<<<E_ / 256, 256, 0, stream>>>(smaxO, score, denO, et, dst);
  zbuild_kernel<<<E_ / 4, 256, 0, stream>>>(rel_out, score, denO, et, dst, zbuf);
  gemm_kernel<0, 0><<<dim3(N_ / BM, C_ / BN, 1), 256, 0, stream>>>(
      zbuf, 0L, R_ * C_, WtR2O, 0L, R_ * C_, aggO, 0L, C_);

  // ---- node_emb ----
  final_kernel<<<N_, 256, 0, stream>>>(nf, aggS, aggO, cntS, cntO, node_out);

  (void)in_sizes; (void)n_in; (void)out_size; (void)ws_size; (void)d_in;
}

// Round 2
// 1084.271 us; speedup vs baseline: 2.6200x; 2.6200x over previous
//
#include <hip/hip_runtime.h>

#define N_ 16384
#define E_ 262144
#define C_ 256
#define R_ 9
#define B_ 4
#define NKEY (N_ * R_)  // 147456

typedef unsigned short u16;
typedef unsigned int u32;

typedef __bf16 bf16x8 __attribute__((ext_vector_type(8)));
typedef float f32x4 __attribute__((ext_vector_type(4)));

__device__ __forceinline__ u16 f2bf(float x) {
  u32 u = __float_as_uint(x);
  u32 r = (u + 0x7fffu + ((u >> 16) & 1u)) >> 16;  // RNE
  return (u16)r;
}
__device__ __forceinline__ float bf2f(u16 h) {
  return __uint_as_float(((u32)h) << 16);
}

// ---------------------------------------------------------------------------
// prep: W_t[r][o][c] (or stacked W_t[o][r*256+c]) = sum_b att[r,b]*basis[b,c,o]
// ---------------------------------------------------------------------------
__global__ void prep_w_kernel(const float* __restrict__ basis,
                              const float* __restrict__ att,
                              u16* __restrict__ out, int stacked) {
  int c = blockIdx.x;    // input channel (K index)
  int r = blockIdx.y;
  int o = threadIdx.x;   // output channel (N index)
  float s = 0.f;
#pragma unroll
  for (int b = 0; b < B_; ++b)
    s += att[r * B_ + b] * basis[((long)b * C_ + c) * C_ + o];
  u16 h = f2bf(s);
  if (stacked) out[(long)o * (R_ * C_) + r * C_ + c] = h;   // Bt[n=o][k=r*256+c]
  else         out[((long)r * C_ + o) * C_ + c] = h;        // per-batch Bt[n=o][k=c]
}

// v[r][c] = sum_o W[r][c][o] * aw[r][o]
__global__ void prep_v_kernel(const float* __restrict__ basis,
                              const float* __restrict__ att,
                              const float* __restrict__ aw,
                              float* __restrict__ v) {
  int c = blockIdx.x, r = blockIdx.y, o = threadIdx.x;
  float w = 0.f;
#pragma unroll
  for (int b = 0; b < B_; ++b)
    w += att[r * B_ + b] * basis[((long)b * C_ + c) * C_ + o];
  float p = w * aw[r * C_ + o];
  __shared__ float red[256];
  red[o] = p;
  __syncthreads();
  for (int s = 128; s > 0; s >>= 1) {
    if (o < s) red[o] += red[o + s];
    __syncthreads();
  }
  if (o == 0) v[r * C_ + c] = red[0];
}

__global__ void cvt_bf16_kernel(const float* __restrict__ in, u16* __restrict__ out) {
  long i = ((long)blockIdx.x * 256 + threadIdx.x) * 4;
  float4 f = *(const float4*)(in + i);
  ushort4 h;
  h.x = f2bf(f.x); h.y = f2bf(f.y); h.z = f2bf(f.z); h.w = f2bf(f.w);
  *(ushort4*)(out + i) = h;
}

// ---------------------------------------------------------------------------
// GEMM: Out[m][n] = sum_k A[m][k] * Bt[n][k]   (Bt is N-major, bf16)
// Tile 128x128x32, 4 waves (2x2), each wave 4x4 mfma_f32_16x16x32_bf16
// ---------------------------------------------------------------------------
#define BM 128
#define BN 128
#define BK 32
#define LSTR 40  // padded LDS row stride (u16 elems)

template <int OBF16>
__global__ __launch_bounds__(256) void gemm_kernel(
    const u16* __restrict__ A, long aBatch, int lda,
    const u16* __restrict__ Bt, long bBatch, int K,
    void* __restrict__ Out, long cBatch, int ldc) {
  __shared__ __attribute__((aligned(16))) u16 As[BM * LSTR];
  __shared__ __attribute__((aligned(16))) u16 Bs[BN * LSTR];

  const int t = threadIdx.x;
  const int m0 = blockIdx.x * BM;
  const int n0 = blockIdx.y * BN;
  const long zb = blockIdx.z;

  const int tr = t >> 1;          // staging row 0..127
  const int th = (t & 1) * 16;    // staging k-offset 0/16

  const int w = t >> 6, lane = t & 63;
  const int wm = (w >> 1) * 64, wn = (w & 1) * 64;
  const int lr = lane & 15;
  const int lk = (lane >> 4) * 8;

  f32x4 acc[4][4];
#pragma unroll
  for (int i = 0; i < 4; ++i)
#pragma unroll
    for (int j = 0; j < 4; ++j) acc[i][j] = (f32x4){0.f, 0.f, 0.f, 0.f};

  const u16* aRow = A + zb * aBatch + (long)(m0 + tr) * lda + th;
  const u16* bRow = Bt + zb * bBatch + (long)(n0 + tr) * K + th;

  u16* aDst = &As[tr * LSTR + th];
  u16* bDst = &Bs[tr * LSTR + th];

  for (int k0 = 0; k0 < K; k0 += BK) {
    int4 a0 = *(const int4*)(aRow);
    int4 a1 = *(const int4*)(aRow + 8);
    int4 b0 = *(const int4*)(bRow);
    int4 b1 = *(const int4*)(bRow + 8);
    *(int4*)(aDst) = a0;
    *(int4*)(aDst + 8) = a1;
    *(int4*)(bDst) = b0;
    *(int4*)(bDst + 8) = b1;
    aRow += BK;
    bRow += BK;
    __syncthreads();

    bf16x8 af[4], bg[4];
#pragma unroll
    for (int mi = 0; mi < 4; ++mi)
      af[mi] = *(const bf16x8*)&As[(wm + mi * 16 + lr) * LSTR + lk];
#pragma unroll
    for (int ni = 0; ni < 4; ++ni)
      bg[ni] = *(const bf16x8*)&Bs[(wn + ni * 16 + lr) * LSTR + lk];
#pragma unroll
    for (int mi = 0; mi < 4; ++mi)
#pragma unroll
      for (int ni = 0; ni < 4; ++ni)
        acc[mi][ni] = __builtin_amdgcn_mfma_f32_16x16x32_bf16(af[mi], bg[ni], acc[mi][ni], 0, 0, 0);

    __syncthreads();
  }

  long base = zb * cBatch;
#pragma unroll
  for (int mi = 0; mi < 4; ++mi) {
    int rowb = m0 + wm + mi * 16 + ((lane >> 4) * 4);
#pragma unroll
    for (int ni = 0; ni < 4; ++ni) {
      int col = n0 + wn + ni * 16 + lr;
      f32x4 c = acc[mi][ni];
#pragma unroll
      for (int i = 0; i < 4; ++i) {
        long idx = base + (long)(rowb + i) * ldc + col;
        if (OBF16) ((u16*)Out)[idx] = f2bf(c[i]);
        else ((float*)Out)[idx] = c[i];
      }
    }
  }
}

// ---------------------------------------------------------------------------
// rel_emb + fused scores for both branches + key histograms
// 1 wave per edge, lane covers 4 channels
// ---------------------------------------------------------------------------
__global__ __launch_bounds__(256) void relemb_kernel(
    const float* __restrict__ ef, const u16* __restrict__ Ysub,
    const u16* __restrict__ Yobj, const int* __restrict__ src,
    const int* __restrict__ dst, const int* __restrict__ et,
    const int* __restrict__ eti, const float* __restrict__ vS,
    const float* __restrict__ abS, const float* __restrict__ vO,
    const float* __restrict__ abO, float* __restrict__ rel,
    float* __restrict__ scoreS, float* __restrict__ scoreO,
    int* __restrict__ cntS, int* __restrict__ cntO) {
  int e = blockIdx.x * 4 + (threadIdx.x >> 6);
  int lane = threadIdx.x & 63;
  int c = lane * 4;
  int sn = src[e], dn = dst[e], tf = et[e], ti = eti[e];
  long rsub = ((long)tf * N_ + sn) * C_ + c;
  long robj = ((long)ti * N_ + dn) * C_ + c;
  ushort4 ys = *(const ushort4*)(Ysub + rsub);
  ushort4 yo = *(const ushort4*)(Yobj + robj);
  long ei = (long)e * C_ + c;
  float4 f = *(const float4*)(ef + ei);
  float4 o;
  o.x = f.x + 0.5f * (bf2f(ys.x) + bf2f(yo.x));
  o.y = f.y + 0.5f * (bf2f(ys.y) + bf2f(yo.y));
  o.z = f.z + 0.5f * (bf2f(ys.z) + bf2f(yo.z));
  o.w = f.w + 0.5f * (bf2f(ys.w) + bf2f(yo.w));
  *(float4*)(rel + ei) = o;

  float4 wS = *(const float4*)(vS + ti * C_ + c);
  float4 wO = *(const float4*)(vO + tf * C_ + c);
  float pS = o.x * wS.x + o.y * wS.y + o.z * wS.z + o.w * wS.w;
  float pO = o.x * wO.x + o.y * wO.y + o.z * wO.z + o.w * wO.w;
#pragma unroll
  for (int off = 32; off > 0; off >>= 1) {
    pS += __shfl_xor(pS, off);
    pO += __shfl_xor(pO, off);
  }
  if (lane == 0) {
    float sS = pS + abS[ti];
    sS = sS > 0.f ? sS : 0.01f * sS;
    scoreS[e] = sS;
    atomicAdd(&cntS[sn * R_ + ti], 1);
    float sO = pO + abO[tf];
    sO = sO > 0.f ? sO : 0.01f * sO;
    scoreO[e] = sO;
    atomicAdd(&cntO[dn * R_ + tf], 1);
  }
}

// ---------------------------------------------------------------------------
// hierarchical exclusive scan over NKEY=147456 counts (144 x 1024)
// ---------------------------------------------------------------------------
__global__ __launch_bounds__(256) void scan1_kernel(const int* __restrict__ cnt,
                                                    int* __restrict__ offs,
                                                    int* __restrict__ part) {
  __shared__ int lds[256];
  int b = blockIdx.x, t = threadIdx.x;
  int base = b * 1024 + t * 4;
  int4 v = *(const int4*)(cnt + base);
  int tsum = v.x + v.y + v.z + v.w;
  lds[t] = tsum;
  __syncthreads();
  for (int d = 1; d < 256; d <<= 1) {
    int x = (t >= d) ? lds[t - d] : 0;
    __syncthreads();
    lds[t] += x;
    __syncthreads();
  }
  int run = (t == 0) ? 0 : lds[t - 1];
  int4 o;
  o.x = run;
  o.y = run + v.x;
  o.z = o.y + v.y;
  o.w = o.z + v.z;
  *(int4*)(offs + base) = o;
  if (t == 255) part[b] = lds[255];
}

__global__ __launch_bounds__(256) void scan2_kernel(int* __restrict__ part) {
  __shared__ int lds[256];
  int t = threadIdx.x;
  lds[t] = (t < 144) ? part[t] : 0;
  __syncthreads();
  for (int d = 1; d < 256; d <<= 1) {
    int x = (t >= d) ? lds[t - d] : 0;
    __syncthreads();
    lds[t] += x;
    __syncthreads();
  }
  if (t < 144) part[t] = (t == 0) ? 0 : lds[t - 1];
}

__global__ __launch_bounds__(256) void scan3_kernel(const int* __restrict__ part,
                                                    int* __restrict__ offs,
                                                    int* __restrict__ cursor) {
  int i = blockIdx.x * 256 + threadIdx.x;  // grid 576
  int v = offs[i] + part[i >> 10];
  offs[i] = v;
  cursor[i] = v;
}

__global__ __launch_bounds__(256) void scatter_kernel(
    const int* __restrict__ etype, const int* __restrict__ seg,
    int* __restrict__ cursor, int* __restrict__ order) {
  int e = blockIdx.x * 256 + threadIdx.x;
  int key = seg[e] * R_ + etype[e];
  int idx = atomicAdd(&cursor[key], 1);
  order[idx] = e;
}

// ---------------------------------------------------------------------------
// one wave per key: local softmax over the key's edge list, weighted sum of
// rel rows, write one bf16 z row (zeros for empty keys — replaces memset)
// z layout: [n][r*256+c]  (key = n*R + r)
// ---------------------------------------------------------------------------
__global__ __launch_bounds__(256) void zgather_kernel(
    const float* __restrict__ rel, const float* __restrict__ score,
    const int* __restrict__ order, const int* __restrict__ offs,
    const int* __restrict__ cnt, u16* __restrict__ z) {
  int key = blockIdx.x * 4 + (threadIdx.x >> 6);
  int lane = threadIdx.x & 63;
  int c = lane * 4;
  int len = cnt[key];
  int start = offs[key];

  float ax = 0.f, ay = 0.f, az = 0.f, aw = 0.f, den = 0.f;
  if (len > 0) {
    float m = -1e30f;
    for (int i = 0; i < len; ++i) m = fmaxf(m, score[order[start + i]]);
    for (int i = 0; i < len; ++i) {
      int e = order[start + i];
      float ex = __expf(score[e] - m);
      den += ex;
      float4 x = *(const float4*)(rel + (long)e * C_ + c);
      ax += ex * x.x; ay += ex * x.y; az += ex * x.z; aw += ex * x.w;
    }
    float inv = 1.f / den;
    ax *= inv; ay *= inv; az *= inv; aw *= inv;
  }
  int n = key / R_, r = key - n * R_;
  ushort4 h;
  h.x = f2bf(ax); h.y = f2bf(ay); h.z = f2bf(az); h.w = f2bf(aw);
  *(ushort4*)(z + (long)n * (R_ * C_) + r * C_ + c) = h;
}

__global__ __launch_bounds__(256) void final_kernel(
    const float* __restrict__ nf, const float* __restrict__ aggS,
    const float* __restrict__ aggO, const int* __restrict__ cntS,
    const int* __restrict__ cntO, float* __restrict__ node) {
  int n = blockIdx.x, c = threadIdx.x;
  int ds = 0, dobj = 0;
#pragma unroll
  for (int r = 0; r < R_; ++r) {
    ds += (cntS[n * R_ + r] > 0);
    dobj += (cntO[n * R_ + r] > 0);
  }
  float fs = ds ? (float)ds : 1.f;
  float fo = dobj ? (float)dobj : 1.f;
  long i = (long)n * C_ + c;
  node[i] = nf[i] + 0.5f * (aggS[i] / fs + aggO[i] / fo);
}

// ---------------------------------------------------------------------------
extern "C" void kernel_launch(void* const* d_in, const int* in_sizes, int n_in,
                              void* d_out, int out_size, void* d_ws, size_t ws_size,
                              hipStream_t stream) {
  const int* edge_index = (const int*)d_in[0];
  const float* nf = (const float*)d_in[1];
  const float* ef = (const float*)d_in[2];
  const int* et = (const int*)d_in[3];
  const int* eti = (const int*)d_in[4];
  const float* s2r_basis = (const float*)d_in[6];
  const float* s2r_att = (const float*)d_in[7];
  const float* o2r_basis = (const float*)d_in[8];
  const float* o2r_att = (const float*)d_in[9];
  const float* r2s_basis = (const float*)d_in[10];
  const float* r2s_att = (const float*)d_in[11];
  const float* r2s_aw = (const float*)d_in[12];
  const float* r2s_ab = (const float*)d_in[13];
  const float* r2o_basis = (const float*)d_in[14];
  const float* r2o_att = (const float*)d_in[15];
  const float* r2o_aw = (const float*)d_in[16];
  const float* r2o_ab = (const float*)d_in[17];

  const int* src = edge_index;
  const int* dst = edge_index + E_;

  char* ws = (char*)d_ws;
  u16* WtSub = (u16*)(ws + 0);
  u16* WtObj = (u16*)(ws + 1179648);
  u16* WtR2S = (u16*)(ws + 2359296);
  u16* WtR2O = (u16*)(ws + 3538944);
  float* vS = (float*)(ws + 4718592);
  float* vO = (float*)(ws + 4727808);
  u16* nfb = (u16*)(ws + 4737024);       // 8 MB -> 13125632
  float* scoreS = (float*)(ws + 13125632);
  float* scoreO = (float*)(ws + 14174208);
  int* cntS = (int*)(ws + 15222784);
  int* cntO = (int*)(ws + 15812608);
  int* offs = (int*)(ws + 16402432);
  int* cursor = (int*)(ws + 16992256);
  int* order = (int*)(ws + 17582080);    // 1 MB -> 18630656
  int* part = (int*)(ws + 18630656);     // 4 KB
  u16* Ysub = (u16*)(ws + 18634752);     // 75.5 MB -> 94132224
  u16* Yobj = (u16*)(ws + 94132224);     // 75.5 MB -> 169629696
  u16* zbuf = (u16*)(ws + 18634752);     // aliases Ysub (dead after relemb)
  float* aggS = (float*)(ws + 94132224); // aliases Yobj (dead after relemb)
  float* aggO = (float*)(ws + 110909440);

  float* node_out = (float*)d_out;
  float* rel_out = (float*)d_out + (long)N_ * C_;

  // ---- prep ----
  prep_w_kernel<<<dim3(C_, R_), 256, 0, stream>>>(s2r_basis, s2r_att, WtSub, 0);
  prep_w_kernel<<<dim3(C_, R_), 256, 0, stream>>>(o2r_basis, o2r_att, WtObj, 0);
  prep_w_kernel<<<dim3(C_, R_), 256, 0, stream>>>(r2s_basis, r2s_att, WtR2S, 1);
  prep_w_kernel<<<dim3(C_, R_), 256, 0, stream>>>(r2o_basis, r2o_att, WtR2O, 1);
  prep_v_kernel<<<dim3(C_, R_), 256, 0, stream>>>(r2s_basis, r2s_att, r2s_aw, vS);
  prep_v_kernel<<<dim3(C_, R_), 256, 0, stream>>>(r2o_basis, r2o_att, r2o_aw, vO);
  cvt_bf16_kernel<<<(N_ * C_) / 1024, 256, 0, stream>>>(nf, nfb);
  hipMemsetAsync(cntS, 0, 2L * 589824, stream);  // cntS + cntO contiguous

  // ---- Y[r] = nf @ W_r (batched over r), bf16 out ----
  gemm_kernel<1><<<dim3(N_ / BM, C_ / BN, R_), 256, 0, stream>>>(
      nfb, 0L, C_, WtSub, (long)C_ * C_, C_, Ysub, (long)N_ * C_, C_);
  gemm_kernel<1><<<dim3(N_ / BM, C_ / BN, R_), 256, 0, stream>>>(
      nfb, 0L, C_, WtObj, (long)C_ * C_, C_, Yobj, (long)N_ * C_, C_);

  // ---- rel_emb + scores + histograms ----
  relemb_kernel<<<E_ / 4, 256, 0, stream>>>(ef, Ysub, Yobj, src, dst, et, eti,
                                            vS, r2s_ab, vO, r2o_ab, rel_out,
                                            scoreS, scoreO, cntS, cntO);

  // ---- branch rel2sub: etypes = eti, seg = src ----
  scan1_kernel<<<144, 256, 0, stream>>>(cntS, offs, part);
  scan2_kernel<<<1, 256, 0, stream>>>(part);
  scan3_kernel<<<576, 256, 0, stream>>>(part, offs, cursor);
  scatter_kernel<<<E_ / 256, 256, 0, stream>>>(eti, src, cursor, order);
  zgather_kernel<<<NKEY / 4, 256, 0, stream>>>(rel_out, scoreS, order, offs, cntS, zbuf);
  gemm_kernel<0><<<dim3(N_ / BM, C_ / BN, 1), 256, 0, stream>>>(
      zbuf, 0L, R_ * C_, WtR2S, 0L, R_ * C_, aggS, 0L, C_);

  // ---- branch rel2obj: etypes = et, seg = dst ----
  scan1_kernel<<<144, 256, 0, stream>>>(cntO, offs, part);
  scan2_kernel<<<1, 256, 0, stream>>>(part);
  scan3_kernel<<<576, 256, 0, stream>>>(part, offs, cursor);
  scatter_kernel<<<E_ / 256, 256, 0, stream>>>(et, dst, cursor, order);
  zgather_kernel<<<NKEY / 4, 256, 0, stream>>>(rel_out, scoreO, order, offs, cntO, zbuf);
  gemm_kernel<0><<<dim3(N_ / BM, C_ / BN, 1), 256, 0, stream>>>(
      zbuf, 0L, R_ * C_, WtR2O, 0L, R_ * C_, aggO, 0L, C_);

  // ---- node_emb ----
  final_kernel<<<N_, 256, 0, stream>>>(nf, aggS, aggO, cntS, cntO, node_out);

  (void)in_sizes; (void)n_in; (void)out_size; (void)ws_size;
}